// Round 4
// baseline (213.109 us; speedup 1.0000x reference)
//
#include <hip/hip_runtime.h>
#include <hip/hip_bf16.h>
#include <math.h>

typedef __attribute__((ext_vector_type(8))) short short8;
typedef __attribute__((ext_vector_type(4))) short s16x4;
typedef __attribute__((ext_vector_type(4))) float f32x4;

#define SEQ 2048
#define DH 128

__device__ __forceinline__ short f2bf(float f) {
    union { float f; unsigned u; } v; v.f = f;
    unsigned r = v.u + 0x7fffu + ((v.u >> 16) & 1u);
    return (short)(r >> 16);
}
__device__ __forceinline__ float bf2f(short s) {
    union { unsigned u; float f; } v; v.u = ((unsigned)(unsigned short)s) << 16;
    return v.f;
}

__device__ __forceinline__ void gll16(const void* g, void* l) {
    __builtin_amdgcn_global_load_lds(
        (const __attribute__((address_space(1))) unsigned int*)g,
        (__attribute__((address_space(3))) unsigned int*)l, 16, 0, 0);
}

// wave-local LDS fence: all prior ds ops complete, nothing crosses
__device__ __forceinline__ void wave_lds_fence() {
    asm volatile("s_waitcnt lgkmcnt(0)" ::: "memory");
    __builtin_amdgcn_sched_barrier(0);
}

// ---------------- Wt2: frag-linear bf16 W ----------------
__global__ __launch_bounds__(256) void wt_kernel(
    const float* __restrict__ Wq, const float* __restrict__ Wk, const float* __restrict__ Wv,
    short* __restrict__ Wt2)
{
    const int t = threadIdx.x;
    const int m  = blockIdx.x >> 4;
    const int ks = blockIdx.x & 15;
    const float* W = m == 0 ? Wq : (m == 1 ? Wk : Wv);
    short* dst = Wt2 + ((size_t)(m * 16 + ks) * 1024) * 8;
    #pragma unroll
    for (int j = 0; j < 4; j++) {
        const int idx = t * 4 + j;
        const int ctile = idx >> 7;
        const int kc = (idx >> 6) & 1;
        const int gg = (idx >> 4) & 3;
        const int cc = idx & 15;
        const int col = ctile * 16 + cc;
        const int kb = ks * 64 + kc * 32 + gg * 8;
        short8 h;
        #pragma unroll
        for (int e = 0; e < 8; e++) h[e] = f2bf(W[(size_t)(kb + e) * 128 + col]);
        *(short8*)&dst[idx * 8] = h;
    }
}

// ---------------- proj: Qh,Kh,Vh (bf16) = x @ W, tiled MFMA ----------------
__global__ __launch_bounds__(256) void proj_kernel(
    const float* __restrict__ x, const short* __restrict__ Wt2,
    short* __restrict__ Qh, short* __restrict__ Kh, short* __restrict__ Vh)
{
    __shared__ short Xs[2048];
    __shared__ short Ws[8192];
    const int t = threadIdx.x;
    const int w = t >> 6, l = t & 63;
    const int c = l & 15, g = l >> 4;
    const int bid = blockIdx.x;
    const int m = bid % 3;
    const int row0 = (bid / 3) * 32;
    const short* Wm = Wt2 + (size_t)m * 16 * 1024 * 8;

    const int xr = t >> 3;
    const int xk = (t & 7) * 8;
    const int xIdx = ((xr >> 4) * 2 + (xk >> 5)) * 64 + ((xk >> 3) & 3) * 16 + (xr & 15);

    const int rt = w & 1;
    const int ct4 = (w >> 1) * 4;
    f32x4 acc[4];
    #pragma unroll
    for (int nt = 0; nt < 4; nt++) acc[nt] = (f32x4)0.f;

    for (int ks = 0; ks < 16; ks++) {
        __syncthreads();
        const short* wsrc = Wm + ((size_t)ks * 1024 + w * 256 + l) * 8;
        #pragma unroll
        for (int j = 0; j < 4; j++)
            gll16(wsrc + j * 64 * 8, (void*)&Ws[(w * 256 + j * 64) * 8]);
        {
            const float* xp = &x[(size_t)(row0 + xr) * 1024 + ks * 64 + xk];
            const float4 a = *(const float4*)xp;
            const float4 b = *(const float4*)(xp + 4);
            short8 h;
            h[0] = f2bf(a.x); h[1] = f2bf(a.y); h[2] = f2bf(a.z); h[3] = f2bf(a.w);
            h[4] = f2bf(b.x); h[5] = f2bf(b.y); h[6] = f2bf(b.z); h[7] = f2bf(b.w);
            *(short8*)&Xs[xIdx * 8] = h;
        }
        __syncthreads();
        #pragma unroll
        for (int kc = 0; kc < 2; kc++) {
            const short8 af = *(const short8*)&Xs[((rt * 2 + kc) * 64 + l) * 8];
            #pragma unroll
            for (int nt = 0; nt < 4; nt++) {
                const short8 bf = *(const short8*)&Ws[(((ct4 + nt) * 2 + kc) * 64 + l) * 8];
                acc[nt] = __builtin_amdgcn_mfma_f32_16x16x32_bf16(af, bf, acc[nt], 0, 0, 0);
            }
        }
    }
    short* Out = m == 0 ? Qh : (m == 1 ? Kh : Vh);
    #pragma unroll
    for (int nt = 0; nt < 4; nt++)
        #pragma unroll
        for (int r = 0; r < 4; r++)
            Out[(size_t)(row0 + rt * 16 + 4 * g + r) * 128 + (ct4 + nt) * 16 + c] = f2bf(acc[nt][r]);
}

// ---------------- y = K @ L (f32 acc), Yh bf16 + SQ from rounded y ----------------
__global__ __launch_bounds__(256) void y_kernel(
    const short* __restrict__ Kh, const float* __restrict__ L,
    short* __restrict__ Yh, float* __restrict__ SQ)
{
    __shared__ float Ls[128 * 128];
    __shared__ short Ks[16][128];
    const int t = threadIdx.x;
    const int row0 = blockIdx.x * 16;
    #pragma unroll
    for (int j = 0; j < 16; j++) {
        int lin = t + j * 256;
        ((float4*)Ls)[lin] = ((const float4*)L)[lin];
    }
    {
        int r = t >> 4, ch = t & 15;
        *(short8*)&Ks[r][ch * 8] = *(const short8*)&Kh[(size_t)(row0 + r) * 128 + ch * 8];
    }
    __syncthreads();
    const int rl = t >> 4, c4 = (t & 15) * 4;
    float acc[8] = {};
    for (int d = 0; d < 128; d++) {
        const float kd = bf2f(Ks[rl][d]);
        const float4 l0 = *(const float4*)&Ls[d * 128 + c4];
        const float4 l1 = *(const float4*)&Ls[d * 128 + c4 + 64];
        acc[0] += kd * l0.x; acc[1] += kd * l0.y; acc[2] += kd * l0.z; acc[3] += kd * l0.w;
        acc[4] += kd * l1.x; acc[5] += kd * l1.y; acc[6] += kd * l1.z; acc[7] += kd * l1.w;
    }
    const int row = row0 + rl;
    s16x4 h0, h1;
    float s = 0.f;
    #pragma unroll
    for (int j = 0; j < 4; j++) {
        short h = f2bf(acc[j]);     float rv = bf2f(h); s += rv * rv; h0[j] = h;
        short g = f2bf(acc[j + 4]); float gv = bf2f(g); s += gv * gv; h1[j] = g;
    }
    *(s16x4*)&Yh[(size_t)row * 128 + c4]      = h0;
    *(s16x4*)&Yh[(size_t)row * 128 + c4 + 64] = h1;
    for (int off = 1; off < 16; off <<= 1) s += __shfl_xor(s, off);
    if ((t & 15) == 0) SQ[row] = s;
}

// ---------------- Vt[b][d 128][key 2048] = Vh[b][key][d] ----------------
__global__ __launch_bounds__(256) void vt_kernel(
    const short* __restrict__ Vh, short* __restrict__ Vt)
{
    __shared__ short Ls[64][72];
    const int t = threadIdx.x;
    const int b  = blockIdx.x >> 6;
    const int nb = (blockIdx.x >> 1) & 31;
    const int db = blockIdx.x & 1;
    const int n0 = nb * 64, d0 = db * 64;
    const short* Vb = Vh + (size_t)b * SEQ * 128;
    short* Vtb = Vt + (size_t)b * 128 * SEQ;
    #pragma unroll
    for (int i = 0; i < 2; i++) {
        int row = (t >> 3) + 32 * i;
        int ch = t & 7;
        *(short8*)&Ls[row][ch * 8] = *(const short8*)&Vb[(size_t)(n0 + row) * 128 + d0 + ch * 8];
    }
    __syncthreads();
    #pragma unroll
    for (int i = 0; i < 2; i++) {
        int dd = (t >> 3) + 32 * i;
        int nc = t & 7;
        short8 v;
        #pragma unroll
        for (int j = 0; j < 8; j++) v[j] = Ls[nc * 8 + j][dd];
        *(short8*)&Vtb[(size_t)(d0 + dd) * SEQ + n0 + nc * 8] = v;
    }
}

// ---------------- fused dual attention, MFMA, no global atomics ----------------
// 512 blocks = grav(2) x b(4) x qt(64, LPT order), 4 waves each.
// Waves split key-tiles; merge via LDS ds_add_f32; block owns output tile.
__global__ __launch_bounds__(256, 4) void attn_kernel(
    const short* __restrict__ Qh, const short* __restrict__ Kh,
    const short* __restrict__ Yh, const short* __restrict__ Vt,
    const float* __restrict__ SQv,
    float* __restrict__ OL, float* __restrict__ OG,
    float* __restrict__ LS, float* __restrict__ GS)
{
    __shared__ short P[4 * 2048];       // per-wave 4 KB swizzled P slices
    __shared__ float Obuf[32][132];     // f32 merge buffer (stride 132: free 2-way)
    __shared__ float Rs[32];
    const int t = threadIdx.x;
    const int w = t >> 6, l = t & 63;
    const int c = l & 15, g = l >> 4;
    const int bid = blockIdx.x;
    const int qt = 63 - (bid >> 3);     // heavy tiles dispatch first (LPT)
    const int b = bid & 3;
    const int grav = (bid >> 2) & 1;
    const int q0 = qt * 32;
    const int nkt = (qt + 2) >> 1;      // # 64-key tiles

    // zero merge buffers
    for (int i = t; i < 32 * 132; i += 256) ((float*)Obuf)[i] = 0.f;
    if (t < 32) Rs[t] = 0.f;
    __syncthreads();

    const size_t boff = (size_t)b * SEQ * 128;
    const short* Ab = (grav ? Yh : Qh) + boff;
    const short* Bb = (grav ? Yh : Kh) + boff;
    const short* Vb = Vt + boff;
    const float* SQb = SQv + b * SEQ;
    short* Pw = P + w * 2048;

    short8 qf[2][4];
    #pragma unroll
    for (int mt = 0; mt < 2; mt++)
        #pragma unroll
        for (int kc = 0; kc < 4; kc++)
            qf[mt][kc] = *(const short8*)&Ab[(size_t)(q0 + mt * 16 + c) * 128 + kc * 32 + 8 * g];

    float sqq[2][4];
    if (grav) {
        #pragma unroll
        for (int mt = 0; mt < 2; mt++)
            #pragma unroll
            for (int r = 0; r < 4; r++)
                sqq[mt][r] = SQb[q0 + mt * 16 + 4 * g + r];
    }

    f32x4 acc[2][8];
    #pragma unroll
    for (int mt = 0; mt < 2; mt++)
        #pragma unroll
        for (int dt = 0; dt < 8; dt++) acc[mt][dt] = (f32x4)0.f;
    float rsum[2][4] = {};

    for (int tt = w; tt < nkt; tt += 4) {
        const int k0 = tt * 64;
        #pragma unroll
        for (int kt = 0; kt < 4; kt++) {
            const int kbase = k0 + kt * 16;
            if (kbase <= q0 + 31) {
                short8 bf[4];
                #pragma unroll
                for (int kc = 0; kc < 4; kc++)
                    bf[kc] = *(const short8*)&Bb[(size_t)(kbase + c) * 128 + kc * 32 + 8 * g];
                const float sqk = grav ? SQb[kbase + c] : 0.f;
                #pragma unroll
                for (int mt = 0; mt < 2; mt++) {
                    f32x4 sc = (f32x4)0.f;
                    #pragma unroll
                    for (int kc = 0; kc < 4; kc++)
                        sc = __builtin_amdgcn_mfma_f32_16x16x32_bf16(qf[mt][kc], bf[kc], sc, 0, 0, 0);
                    #pragma unroll
                    for (int r = 0; r < 4; r++) {
                        const int qrow = q0 + mt * 16 + 4 * g + r;
                        const int key = kbase + c;
                        float p = 0.f;
                        if (key <= qrow) {
                            if (grav) {
                                float d2 = sqq[mt][r] + sqk - 2.f * sc[r];
                                d2 = fmaxf(d2, 0.f);
                                p = __expf(d2 * -0.00390625f);
                            } else {
                                p = __expf(sc[r] * 0.08838834764831845f);
                            }
                        }
                        const short ph = f2bf(p);
                        rsum[mt][r] += bf2f(ph);
                        const int row = mt * 16 + 4 * g + r;
                        Pw[((row * 128 + (kt * 16 + c) * 2) ^ ((row & 7) << 4)) >> 1] = ph;
                    }
                }
            } else {
                #pragma unroll
                for (int mt = 0; mt < 2; mt++)
                    #pragma unroll
                    for (int r = 0; r < 4; r++) {
                        const int row = mt * 16 + 4 * g + r;
                        Pw[((row * 128 + (kt * 16 + c) * 2) ^ ((row & 7) << 4)) >> 1] = 0;
                    }
            }
        }
        wave_lds_fence();   // P writes visible within wave
        short8 pf[2][2];
        #pragma unroll
        for (int mt = 0; mt < 2; mt++)
            #pragma unroll
            for (int kc = 0; kc < 2; kc++) {
                const int row = mt * 16 + c;
                const int off = (row * 128 + 16 * g + 64 * kc) ^ ((row & 7) << 4);
                pf[mt][kc] = *(const short8*)((const char*)Pw + off);
            }
        #pragma unroll
        for (int dt = 0; dt < 8; dt++) {
            #pragma unroll
            for (int kc = 0; kc < 2; kc++) {
                const short8 vf = *(const short8*)&Vb[(size_t)(dt * 16 + c) * SEQ + k0 + kc * 32 + 8 * g];
                #pragma unroll
                for (int mt = 0; mt < 2; mt++)
                    acc[mt][dt] = __builtin_amdgcn_mfma_f32_16x16x32_bf16(pf[mt][kc], vf, acc[mt][dt], 0, 0, 0);
            }
        }
        wave_lds_fence();   // P reads done before next-iter writes
    }

    // merge partial O into LDS (ds_add_f32)
    #pragma unroll
    for (int mt = 0; mt < 2; mt++)
        #pragma unroll
        for (int dt = 0; dt < 8; dt++)
            #pragma unroll
            for (int r = 0; r < 4; r++)
                atomicAdd(&Obuf[mt * 16 + 4 * g + r][dt * 16 + c], acc[mt][dt][r]);

    // row sums: reduce over c lanes, then LDS add
    #pragma unroll
    for (int mt = 0; mt < 2; mt++)
        #pragma unroll
        for (int r = 0; r < 4; r++) {
            float v = rsum[mt][r];
            v += __shfl_xor(v, 1); v += __shfl_xor(v, 2);
            v += __shfl_xor(v, 4); v += __shfl_xor(v, 8);
            rsum[mt][r] = v;
        }
    if (c == 0) {
        #pragma unroll
        for (int mt = 0; mt < 2; mt++)
            #pragma unroll
            for (int r = 0; r < 4; r++)
                atomicAdd(&Rs[mt * 16 + 4 * g + r], rsum[mt][r]);
    }
    __syncthreads();

    // exclusive streaming writeout
    float* Op = (grav ? OG : OL) + boff + (size_t)q0 * 128;
    #pragma unroll
    for (int i = 0; i < 4; i++) {
        const int v = t + 256 * i;
        const int row = v >> 5, c4 = (v & 31) * 4;
        *(float4*)&Op[row * 128 + c4] = *(const float4*)&Obuf[row][c4];
    }
    if (t < 32) (grav ? GS : LS)[b * SEQ + q0 + t] = Rs[t];
}

// ---------------- finalize: out = 0.7*OL/LS + 0.3*OG/(GS+1e-8) ----------------
__global__ __launch_bounds__(256) void finalize_kernel(
    float* __restrict__ out, const float* __restrict__ OG,
    const float* __restrict__ LS, const float* __restrict__ GS)
{
    const int i4 = blockIdx.x * 256 + threadIdx.x;
    float4 o = ((float4*)out)[i4];
    const float4 gv = ((const float4*)OG)[i4];
    const int row = i4 >> 5;
    const float wl = 0.7f / LS[row];
    const float wg = 0.3f / (GS[row] + 1e-8f);
    o.x = o.x * wl + gv.x * wg;
    o.y = o.y * wl + gv.y * wg;
    o.z = o.z * wl + gv.z * wg;
    o.w = o.w * wl + gv.w * wg;
    ((float4*)out)[i4] = o;
}

extern "C" void kernel_launch(void* const* d_in, const int* in_sizes, int n_in,
                              void* d_out, int out_size, void* d_ws, size_t ws_size,
                              hipStream_t stream) {
    const float* x  = (const float*)d_in[0];
    const float* Wq = (const float*)d_in[1];
    const float* Wk = (const float*)d_in[2];
    const float* Wv = (const float*)d_in[3];
    const float* Lg = (const float*)d_in[4];

    char* ws = (char*)d_ws;
    short* Qh  = (short*)(ws + 0);
    short* Kh  = (short*)(ws + 2097152);
    short* Vh  = (short*)(ws + 4194304);
    short* Yh  = (short*)(ws + 6291456);
    short* Vt  = (short*)(ws + 8388608);
    short* Wt2 = (short*)(ws + 10485760);
    float* SQv = (float*)(ws + 11272192);
    float* LS  = (float*)(ws + 11304960);
    float* GS  = (float*)(ws + 11337728);
    float* OG  = (float*)(ws + 11370496);
    float* OL  = (float*)d_out;

    wt_kernel<<<48, 256, 0, stream>>>(Wq, Wk, Wv, Wt2);
    proj_kernel<<<768, 256, 0, stream>>>(x, Wt2, Qh, Kh, Vh);
    y_kernel<<<512, 256, 0, stream>>>(Kh, Lg, Yh, SQv);
    vt_kernel<<<256, 256, 0, stream>>>(Vh, Vt);
    attn_kernel<<<512, 256, 0, stream>>>(Qh, Kh, Yh, Vt, SQv, OL, OG, LS, GS);
    finalize_kernel<<<1024, 256, 0, stream>>>((float*)d_out, OG, LS, GS);
}

// Round 5
// 128.782 us; speedup vs baseline: 1.6548x; 1.6548x over previous
//
#include <hip/hip_runtime.h>
#include <hip/hip_bf16.h>
#include <math.h>

typedef __attribute__((ext_vector_type(8))) short short8;
typedef __attribute__((ext_vector_type(4))) short s16x4;
typedef __attribute__((ext_vector_type(4))) float f32x4;

#define SEQ 2048
#define DH 128

__device__ __forceinline__ short f2bf(float f) {
    union { float f; unsigned u; } v; v.f = f;
    unsigned r = v.u + 0x7fffu + ((v.u >> 16) & 1u);
    return (short)(r >> 16);
}
__device__ __forceinline__ float bf2f(short s) {
    union { unsigned u; float f; } v; v.u = ((unsigned)(unsigned short)s) << 16;
    return v.f;
}

__device__ __forceinline__ void gll16(const void* g, void* l) {
    __builtin_amdgcn_global_load_lds(
        (const __attribute__((address_space(1))) unsigned int*)g,
        (__attribute__((address_space(3))) unsigned int*)l, 16, 0, 0);
}

// wave-local LDS fence: all prior ds ops complete, nothing crosses
__device__ __forceinline__ void wave_lds_fence() {
    asm volatile("s_waitcnt lgkmcnt(0)" ::: "memory");
    __builtin_amdgcn_sched_barrier(0);
}

// ---------------- Wt2: frag-linear bf16 W ----------------
__global__ __launch_bounds__(256) void wt_kernel(
    const float* __restrict__ Wq, const float* __restrict__ Wk, const float* __restrict__ Wv,
    short* __restrict__ Wt2)
{
    const int t = threadIdx.x;
    const int m  = blockIdx.x >> 4;
    const int ks = blockIdx.x & 15;
    const float* W = m == 0 ? Wq : (m == 1 ? Wk : Wv);
    short* dst = Wt2 + ((size_t)(m * 16 + ks) * 1024) * 8;
    #pragma unroll
    for (int j = 0; j < 4; j++) {
        const int idx = t * 4 + j;
        const int ctile = idx >> 7;
        const int kc = (idx >> 6) & 1;
        const int gg = (idx >> 4) & 3;
        const int cc = idx & 15;
        const int col = ctile * 16 + cc;
        const int kb = ks * 64 + kc * 32 + gg * 8;
        short8 h;
        #pragma unroll
        for (int e = 0; e < 8; e++) h[e] = f2bf(W[(size_t)(kb + e) * 128 + col]);
        *(short8*)&dst[idx * 8] = h;
    }
}

// ---------------- proj: Qh,Kh,Vh (bf16) = x @ W, tiled MFMA ----------------
__global__ __launch_bounds__(256) void proj_kernel(
    const float* __restrict__ x, const short* __restrict__ Wt2,
    short* __restrict__ Qh, short* __restrict__ Kh, short* __restrict__ Vh)
{
    __shared__ short Xs[2048];
    __shared__ short Ws[8192];
    const int t = threadIdx.x;
    const int w = t >> 6, l = t & 63;
    const int c = l & 15, g = l >> 4;
    const int bid = blockIdx.x;
    const int m = bid % 3;
    const int row0 = (bid / 3) * 32;
    const short* Wm = Wt2 + (size_t)m * 16 * 1024 * 8;

    const int xr = t >> 3;
    const int xk = (t & 7) * 8;
    const int xIdx = ((xr >> 4) * 2 + (xk >> 5)) * 64 + ((xk >> 3) & 3) * 16 + (xr & 15);

    const int rt = w & 1;
    const int ct4 = (w >> 1) * 4;
    f32x4 acc[4];
    #pragma unroll
    for (int nt = 0; nt < 4; nt++) acc[nt] = (f32x4)0.f;

    for (int ks = 0; ks < 16; ks++) {
        __syncthreads();
        const short* wsrc = Wm + ((size_t)ks * 1024 + w * 256 + l) * 8;
        #pragma unroll
        for (int j = 0; j < 4; j++)
            gll16(wsrc + j * 64 * 8, (void*)&Ws[(w * 256 + j * 64) * 8]);
        {
            const float* xp = &x[(size_t)(row0 + xr) * 1024 + ks * 64 + xk];
            const float4 a = *(const float4*)xp;
            const float4 b = *(const float4*)(xp + 4);
            short8 h;
            h[0] = f2bf(a.x); h[1] = f2bf(a.y); h[2] = f2bf(a.z); h[3] = f2bf(a.w);
            h[4] = f2bf(b.x); h[5] = f2bf(b.y); h[6] = f2bf(b.z); h[7] = f2bf(b.w);
            *(short8*)&Xs[xIdx * 8] = h;
        }
        __syncthreads();
        #pragma unroll
        for (int kc = 0; kc < 2; kc++) {
            const short8 af = *(const short8*)&Xs[((rt * 2 + kc) * 64 + l) * 8];
            #pragma unroll
            for (int nt = 0; nt < 4; nt++) {
                const short8 bf = *(const short8*)&Ws[(((ct4 + nt) * 2 + kc) * 64 + l) * 8];
                acc[nt] = __builtin_amdgcn_mfma_f32_16x16x32_bf16(af, bf, acc[nt], 0, 0, 0);
            }
        }
    }
    short* Out = m == 0 ? Qh : (m == 1 ? Kh : Vh);
    #pragma unroll
    for (int nt = 0; nt < 4; nt++)
        #pragma unroll
        for (int r = 0; r < 4; r++)
            Out[(size_t)(row0 + rt * 16 + 4 * g + r) * 128 + (ct4 + nt) * 16 + c] = f2bf(acc[nt][r]);
}

// ---------------- y = K @ L (f32 acc), Yh bf16 + SQ from rounded y ----------------
__global__ __launch_bounds__(256) void y_kernel(
    const short* __restrict__ Kh, const float* __restrict__ L,
    short* __restrict__ Yh, float* __restrict__ SQ)
{
    __shared__ float Ls[128 * 128];
    __shared__ short Ks[16][128];
    const int t = threadIdx.x;
    const int row0 = blockIdx.x * 16;
    #pragma unroll
    for (int j = 0; j < 16; j++) {
        int lin = t + j * 256;
        ((float4*)Ls)[lin] = ((const float4*)L)[lin];
    }
    {
        int r = t >> 4, ch = t & 15;
        *(short8*)&Ks[r][ch * 8] = *(const short8*)&Kh[(size_t)(row0 + r) * 128 + ch * 8];
    }
    __syncthreads();
    const int rl = t >> 4, c4 = (t & 15) * 4;
    float acc[8] = {};
    for (int d = 0; d < 128; d++) {
        const float kd = bf2f(Ks[rl][d]);
        const float4 l0 = *(const float4*)&Ls[d * 128 + c4];
        const float4 l1 = *(const float4*)&Ls[d * 128 + c4 + 64];
        acc[0] += kd * l0.x; acc[1] += kd * l0.y; acc[2] += kd * l0.z; acc[3] += kd * l0.w;
        acc[4] += kd * l1.x; acc[5] += kd * l1.y; acc[6] += kd * l1.z; acc[7] += kd * l1.w;
    }
    const int row = row0 + rl;
    s16x4 h0, h1;
    float s = 0.f;
    #pragma unroll
    for (int j = 0; j < 4; j++) {
        short h = f2bf(acc[j]);     float rv = bf2f(h); s += rv * rv; h0[j] = h;
        short g = f2bf(acc[j + 4]); float gv = bf2f(g); s += gv * gv; h1[j] = g;
    }
    *(s16x4*)&Yh[(size_t)row * 128 + c4]      = h0;
    *(s16x4*)&Yh[(size_t)row * 128 + c4 + 64] = h1;
    for (int off = 1; off < 16; off <<= 1) s += __shfl_xor(s, off);
    if ((t & 15) == 0) SQ[row] = s;
}

// ---------------- Vt[b][d 128][key 2048] = Vh[b][key][d] ----------------
__global__ __launch_bounds__(256) void vt_kernel(
    const short* __restrict__ Vh, short* __restrict__ Vt)
{
    __shared__ short Ls[64][72];
    const int t = threadIdx.x;
    const int b  = blockIdx.x >> 6;
    const int nb = (blockIdx.x >> 1) & 31;
    const int db = blockIdx.x & 1;
    const int n0 = nb * 64, d0 = db * 64;
    const short* Vb = Vh + (size_t)b * SEQ * 128;
    short* Vtb = Vt + (size_t)b * 128 * SEQ;
    #pragma unroll
    for (int i = 0; i < 2; i++) {
        int row = (t >> 3) + 32 * i;
        int ch = t & 7;
        *(short8*)&Ls[row][ch * 8] = *(const short8*)&Vb[(size_t)(n0 + row) * 128 + d0 + ch * 8];
    }
    __syncthreads();
    #pragma unroll
    for (int i = 0; i < 2; i++) {
        int dd = (t >> 3) + 32 * i;
        int nc = t & 7;
        short8 v;
        #pragma unroll
        for (int j = 0; j < 8; j++) v[j] = Ls[nc * 8 + j][dd];
        *(short8*)&Vtb[(size_t)(d0 + dd) * SEQ + n0 + nc * 8] = v;
    }
}

// ---------------- fused dual attention, MFMA, no global atomics ----------------
// 512 blocks = grav(2) x b(4) x qt(64, LPT order), 4 waves each.
// Waves split key-tiles; merge via LDS ds_add_f32; block owns output tile.
// launch_bounds(256,2): VGPR cap 256 — the kernel needs ~150 live VGPRs
// (acc 64 + qf 32 + staging); (256,4) capped at 64 and spilled everything.
__global__ __launch_bounds__(256, 2) void attn_kernel(
    const short* __restrict__ Qh, const short* __restrict__ Kh,
    const short* __restrict__ Yh, const short* __restrict__ Vt,
    const float* __restrict__ SQv,
    float* __restrict__ OL, float* __restrict__ OG,
    float* __restrict__ LS, float* __restrict__ GS)
{
    __shared__ short P[4 * 2048];       // per-wave 4 KB swizzled P slices
    __shared__ float Obuf[32][132];     // f32 merge buffer (stride 132: free 2-way)
    __shared__ float Rs[32];
    const int t = threadIdx.x;
    const int w = t >> 6, l = t & 63;
    const int c = l & 15, g = l >> 4;
    const int bid = blockIdx.x;
    const int qt = 63 - (bid >> 3);     // heavy tiles dispatch first (LPT)
    const int b = bid & 3;
    const int grav = (bid >> 2) & 1;
    const int q0 = qt * 32;
    const int nkt = (qt + 2) >> 1;      // # 64-key tiles

    // zero merge buffers
    for (int i = t; i < 32 * 132; i += 256) ((float*)Obuf)[i] = 0.f;
    if (t < 32) Rs[t] = 0.f;
    __syncthreads();

    const size_t boff = (size_t)b * SEQ * 128;
    const short* Ab = (grav ? Yh : Qh) + boff;
    const short* Bb = (grav ? Yh : Kh) + boff;
    const short* Vb = Vt + boff;
    const float* SQb = SQv + b * SEQ;
    short* Pw = P + w * 2048;

    short8 qf[2][4];
    #pragma unroll
    for (int mt = 0; mt < 2; mt++)
        #pragma unroll
        for (int kc = 0; kc < 4; kc++)
            qf[mt][kc] = *(const short8*)&Ab[(size_t)(q0 + mt * 16 + c) * 128 + kc * 32 + 8 * g];

    float sqq[2][4];
    if (grav) {
        #pragma unroll
        for (int mt = 0; mt < 2; mt++)
            #pragma unroll
            for (int r = 0; r < 4; r++)
                sqq[mt][r] = SQb[q0 + mt * 16 + 4 * g + r];
    }

    f32x4 acc[2][8];
    #pragma unroll
    for (int mt = 0; mt < 2; mt++)
        #pragma unroll
        for (int dt = 0; dt < 8; dt++) acc[mt][dt] = (f32x4)0.f;
    float rsum[2][4] = {};

    for (int tt = w; tt < nkt; tt += 4) {
        const int k0 = tt * 64;
        #pragma unroll
        for (int kt = 0; kt < 4; kt++) {
            const int kbase = k0 + kt * 16;
            if (kbase <= q0 + 31) {
                short8 bf[4];
                #pragma unroll
                for (int kc = 0; kc < 4; kc++)
                    bf[kc] = *(const short8*)&Bb[(size_t)(kbase + c) * 128 + kc * 32 + 8 * g];
                const float sqk = grav ? SQb[kbase + c] : 0.f;
                #pragma unroll
                for (int mt = 0; mt < 2; mt++) {
                    f32x4 sc = (f32x4)0.f;
                    #pragma unroll
                    for (int kc = 0; kc < 4; kc++)
                        sc = __builtin_amdgcn_mfma_f32_16x16x32_bf16(qf[mt][kc], bf[kc], sc, 0, 0, 0);
                    #pragma unroll
                    for (int r = 0; r < 4; r++) {
                        const int qrow = q0 + mt * 16 + 4 * g + r;
                        const int key = kbase + c;
                        float p = 0.f;
                        if (key <= qrow) {
                            if (grav) {
                                float d2 = sqq[mt][r] + sqk - 2.f * sc[r];
                                d2 = fmaxf(d2, 0.f);
                                p = __expf(d2 * -0.00390625f);
                            } else {
                                p = __expf(sc[r] * 0.08838834764831845f);
                            }
                        }
                        const short ph = f2bf(p);
                        rsum[mt][r] += bf2f(ph);
                        const int row = mt * 16 + 4 * g + r;
                        Pw[((row * 128 + (kt * 16 + c) * 2) ^ ((row & 7) << 4)) >> 1] = ph;
                    }
                }
            } else {
                #pragma unroll
                for (int mt = 0; mt < 2; mt++)
                    #pragma unroll
                    for (int r = 0; r < 4; r++) {
                        const int row = mt * 16 + 4 * g + r;
                        Pw[((row * 128 + (kt * 16 + c) * 2) ^ ((row & 7) << 4)) >> 1] = 0;
                    }
            }
        }
        wave_lds_fence();   // P writes visible within wave
        short8 pf[2][2];
        #pragma unroll
        for (int mt = 0; mt < 2; mt++)
            #pragma unroll
            for (int kc = 0; kc < 2; kc++) {
                const int row = mt * 16 + c;
                const int off = (row * 128 + 16 * g + 64 * kc) ^ ((row & 7) << 4);
                pf[mt][kc] = *(const short8*)((const char*)Pw + off);
            }
        #pragma unroll
        for (int dt = 0; dt < 8; dt++) {
            #pragma unroll
            for (int kc = 0; kc < 2; kc++) {
                const short8 vf = *(const short8*)&Vb[(size_t)(dt * 16 + c) * SEQ + k0 + kc * 32 + 8 * g];
                #pragma unroll
                for (int mt = 0; mt < 2; mt++)
                    acc[mt][dt] = __builtin_amdgcn_mfma_f32_16x16x32_bf16(pf[mt][kc], vf, acc[mt][dt], 0, 0, 0);
            }
        }
        wave_lds_fence();   // P reads done before next-iter writes
    }

    // merge partial O into LDS (ds_add_f32)
    #pragma unroll
    for (int mt = 0; mt < 2; mt++)
        #pragma unroll
        for (int dt = 0; dt < 8; dt++)
            #pragma unroll
            for (int r = 0; r < 4; r++)
                atomicAdd(&Obuf[mt * 16 + 4 * g + r][dt * 16 + c], acc[mt][dt][r]);

    // row sums: reduce over c lanes, then LDS add
    #pragma unroll
    for (int mt = 0; mt < 2; mt++)
        #pragma unroll
        for (int r = 0; r < 4; r++) {
            float v = rsum[mt][r];
            v += __shfl_xor(v, 1); v += __shfl_xor(v, 2);
            v += __shfl_xor(v, 4); v += __shfl_xor(v, 8);
            rsum[mt][r] = v;
        }
    if (c == 0) {
        #pragma unroll
        for (int mt = 0; mt < 2; mt++)
            #pragma unroll
            for (int r = 0; r < 4; r++)
                atomicAdd(&Rs[mt * 16 + 4 * g + r], rsum[mt][r]);
    }
    __syncthreads();

    // exclusive streaming writeout
    float* Op = (grav ? OG : OL) + boff + (size_t)q0 * 128;
    #pragma unroll
    for (int i = 0; i < 4; i++) {
        const int v = t + 256 * i;
        const int row = v >> 5, c4 = (v & 31) * 4;
        *(float4*)&Op[row * 128 + c4] = *(const float4*)&Obuf[row][c4];
    }
    if (t < 32) (grav ? GS : LS)[b * SEQ + q0 + t] = Rs[t];
}

// ---------------- finalize: out = 0.7*OL/LS + 0.3*OG/(GS+1e-8) ----------------
__global__ __launch_bounds__(256) void finalize_kernel(
    float* __restrict__ out, const float* __restrict__ OG,
    const float* __restrict__ LS, const float* __restrict__ GS)
{
    const int i4 = blockIdx.x * 256 + threadIdx.x;
    float4 o = ((float4*)out)[i4];
    const float4 gv = ((const float4*)OG)[i4];
    const int row = i4 >> 5;
    const float wl = 0.7f / LS[row];
    const float wg = 0.3f / (GS[row] + 1e-8f);
    o.x = o.x * wl + gv.x * wg;
    o.y = o.y * wl + gv.y * wg;
    o.z = o.z * wl + gv.z * wg;
    o.w = o.w * wl + gv.w * wg;
    ((float4*)out)[i4] = o;
}

extern "C" void kernel_launch(void* const* d_in, const int* in_sizes, int n_in,
                              void* d_out, int out_size, void* d_ws, size_t ws_size,
                              hipStream_t stream) {
    const float* x  = (const float*)d_in[0];
    const float* Wq = (const float*)d_in[1];
    const float* Wk = (const float*)d_in[2];
    const float* Wv = (const float*)d_in[3];
    const float* Lg = (const float*)d_in[4];

    char* ws = (char*)d_ws;
    short* Qh  = (short*)(ws + 0);
    short* Kh  = (short*)(ws + 2097152);
    short* Vh  = (short*)(ws + 4194304);
    short* Yh  = (short*)(ws + 6291456);
    short* Vt  = (short*)(ws + 8388608);
    short* Wt2 = (short*)(ws + 10485760);
    float* SQv = (float*)(ws + 11272192);
    float* LS  = (float*)(ws + 11304960);
    float* GS  = (float*)(ws + 11337728);
    float* OG  = (float*)(ws + 11370496);
    float* OL  = (float*)d_out;

    wt_kernel<<<48, 256, 0, stream>>>(Wq, Wk, Wv, Wt2);
    proj_kernel<<<768, 256, 0, stream>>>(x, Wt2, Qh, Kh, Vh);
    y_kernel<<<512, 256, 0, stream>>>(Kh, Lg, Yh, SQv);
    vt_kernel<<<256, 256, 0, stream>>>(Vh, Vt);
    attn_kernel<<<512, 256, 0, stream>>>(Qh, Kh, Yh, Vt, SQv, OL, OG, LS, GS);
    finalize_kernel<<<1024, 256, 0, stream>>>((float*)d_out, OG, LS, GS);
}